// Round 22
// baseline (308.848 us; speedup 1.0000x reference)
//
#include <hip/hip_runtime.h>
#include <hip/hip_bf16.h>
#include <cfloat>

typedef __attribute__((ext_vector_type(8))) short bf16x8;
typedef __attribute__((ext_vector_type(4))) float f32x4;

#define M_DIM 8192
#define N_DIM 4096
#define K_DIM 4096

__device__ inline ushort f2bf(float f) {
    unsigned u = __float_as_uint(f);
    unsigned r = (u + 0x7FFFu + ((u >> 16) & 1u)) >> 16;
    return (ushort)r;
}

// swizzle: XOR 16B-slot index (bits 4-6) with row low bits (bits 7-9). Involution.
#define SWZ(x) ((x) ^ ((((x) >> 7) & 7) << 4))

// ---------------- kernel 1: weight 4-bit group-128 quant-dequant -> bf16 (row-major) --
__global__ __launch_bounds__(256) void w_dequant(const float* __restrict__ w,
                                                 ushort* __restrict__ wq) {
    int g = blockIdx.x * 4 + (threadIdx.x >> 6);
    int lane = threadIdx.x & 63;
    const float* src = w + (size_t)g * 128;
    float2 v = *(const float2*)(src + lane * 2);
    float mn = fminf(v.x, v.y), mx = fmaxf(v.x, v.y);
#pragma unroll
    for (int s = 1; s < 64; s <<= 1) {
        mn = fminf(mn, __shfl_xor(mn, s));
        mx = fmaxf(mx, __shfl_xor(mx, s));
    }
    float scale = (mx - mn) / 15.0f;
    float zero  = -8.0f - rintf(mn / scale);
    float q0 = fminf(fmaxf(rintf(v.x / scale) + zero, -8.0f), 7.0f);
    float q1 = fminf(fmaxf(rintf(v.y / scale) + zero, -8.0f), 7.0f);
    ushort2 o;
    o.x = f2bf((q0 - zero) * scale);
    o.y = f2bf((q1 - zero) * scale);
    *(ushort2*)(wq + (size_t)g * 128 + lane * 2) = o;
}

// ---------------- kernel 2: per-row int8 act quant-dequant -> bf16 ----------------
__global__ __launch_bounds__(256) void act_qdq(const float* __restrict__ x,
                                               ushort* __restrict__ xq) {
    __shared__ float smn[4], smx[4];
    int row = blockIdx.x;
    const float* xr = x + (size_t)row * K_DIM;
    ushort* xo = xq + (size_t)row * K_DIM;
    int t = threadIdx.x;
    float4 v[4];
    float mn = FLT_MAX, mx = -FLT_MAX;
#pragma unroll
    for (int i = 0; i < 4; i++) {
        v[i] = ((const float4*)xr)[t + i * 256];
        mn = fminf(mn, fminf(fminf(v[i].x, v[i].y), fminf(v[i].z, v[i].w)));
        mx = fmaxf(mx, fmaxf(fmaxf(v[i].x, v[i].y), fmaxf(v[i].z, v[i].w)));
    }
#pragma unroll
    for (int s = 1; s < 64; s <<= 1) {
        mn = fminf(mn, __shfl_xor(mn, s));
        mx = fmaxf(mx, __shfl_xor(mx, s));
    }
    int w = t >> 6;
    if ((t & 63) == 0) { smn[w] = mn; smx[w] = mx; }
    __syncthreads();
    mn = fminf(fminf(smn[0], smn[1]), fminf(smn[2], smn[3]));
    mx = fmaxf(fmaxf(smx[0], smx[1]), fmaxf(smx[2], smx[3]));
    float scale = (mx - mn) / 255.0f;
    float zero  = -128.0f - rintf(mn / scale);
#pragma unroll
    for (int i = 0; i < 4; i++) {
        ushort4 o;
        float q;
        q = fminf(fmaxf(rintf(v[i].x / scale) + zero, -128.0f), 127.0f); o.x = f2bf((q - zero) * scale);
        q = fminf(fmaxf(rintf(v[i].y / scale) + zero, -128.0f), 127.0f); o.y = f2bf((q - zero) * scale);
        q = fminf(fmaxf(rintf(v[i].z / scale) + zero, -128.0f), 127.0f); o.z = f2bf((q - zero) * scale);
        q = fminf(fmaxf(rintf(v[i].w / scale) + zero, -128.0f), 127.0f); o.w = f2bf((q - zero) * scale);
        ((ushort4*)xo)[t + i * 256] = o;
    }
}

// ---------------- kernel 3: 256x256 bf16 GEMM, (d,kk,h) phases, 4-stage slots --------
// Phases grouped by (buffer d, kk, mi-half h): reads 8/4/8/4 per phase (was 12 at q0).
// Corrected A coverage: rows h*128 + (j>>1)*64 + (j&1)*16 + wm*32 (byte off
// h*16384 + (j>>1)*8192 + (j&1)*2048). Slot table re-derived for the extended B
// lifetime (B[d] dies pos2): stages 4-at-once at pos0 (A[E+1]), pos3 (B[E+2]),
// pos4 (A[E+2]), pos7 (B[E+3]); vmcnt(4) at pos3/pos7 forces all >=3-phase-old
// stages (own 4 stay in flight). All overwrite-after-death + landing audited.
#define BM 256
#define BN 256
#define BK 64
#define NT (K_DIM / BK)   /* 64 K-tiles */

__global__ __launch_bounds__(512, 1) void gemm_bt8(const ushort* __restrict__ A,
                                                   const ushort* __restrict__ B,
                                                   float* __restrict__ C) {
    __shared__ __align__(16) ushort As[2][BM * BK];   // quarter rq at byte rq*8192
    __shared__ __align__(16) ushort Bs[2][BN * BK];

    const int nbx = N_DIM / BN;                 // 16
    const int nwg = (M_DIM / BM) * nbx;         // 512 (%8==0)
    int bid = blockIdx.x;
    bid = (bid & 7) * (nwg / 8) + (bid >> 3);   // bijective XCD swizzle
    int mb = bid / nbx, nb = bid % nbx;
    size_t m0 = (size_t)mb * BM, n0 = (size_t)nb * BN;

    const int t = threadIdx.x;
    const int w = t >> 6, lane = t & 63;
    const int wm = w >> 2, wn = w & 3;          // 2 x 4 wave grid
    const int lr = lane & 15;
    const int lk = (lane >> 4) << 3;

    const ushort* Ab = A + m0 * K_DIM;
    const ushort* Bb = B + n0 * K_DIM;

    // hoisted swizzled lane-parts: phys = row*128 + (colbyte ^ ((lr&7)<<4)), row%8==lr%8
    const int mask7 = (lr & 7) << 4;
    const int lp0 = lr * 128 + ((lk * 2) ^ mask7);          // kk=0
    const int lp1 = lr * 128 + ((64 + lk * 2) ^ mask7);     // kk=1
    const char* A_kb[2] = { (const char*)As + wm * 4096 + lp0,
                            (const char*)As + wm * 4096 + lp1 };
    const char* B_kb[2] = { (const char*)Bs + wn * 8192 + lp0,
                            (const char*)Bs + wn * 8192 + lp1 };

    // hoisted stage source offsets (elements) and dest bytes per row-quarter
    int off_q[4], dst_q[4];
#pragma unroll
    for (int rq = 0; rq < 4; rq++) {
        int base = rq * 8192 + w * 1024;
        int lg = SWZ(base + lane * 16);
        off_q[rq] = (lg >> 7) * K_DIM + ((lg & 127) >> 1);
        dst_q[rq] = base;
    }

    // stage one 8KB quarter: qq 0-3 = A rows qq*64.., qq 4-7 = B rows (qq-4)*64..
    auto STAGE = [&](int T, int qq) {
        if (T >= NT) return;
        int d = T & 1;
        bool isA = qq < 4;
        int rq = qq & 3;
        ushort* l = isA ? As[d] : Bs[d];
        const ushort* g = (isA ? Ab : Bb) + (size_t)T * BK + off_q[rq];
        __builtin_amdgcn_global_load_lds(
            (const __attribute__((address_space(1))) unsigned int*)g,
            (__attribute__((address_space(3))) unsigned int*)((char*)l + dst_q[rq]),
            16, 0, 0);
    };

    f32x4 acc[8][4] = {};
    bf16x8 afr[4];      // 4 A-frags of one (kk, h): rows h*128+(j>>1)*64+(j&1)*16+wm*32
    bf16x8 bfr[4];      // 4 B-frags of one kk, read at h==0, live 2 phases

#define LOADA(d, kk, h) do {                                                      \
    _Pragma("unroll") for (int j = 0; j < 4; j++)                                 \
        afr[j] = *(const bf16x8*)(A_kb[kk] + (d) * 32768 + (h) * 16384            \
                                  + (j >> 1) * 8192 + (j & 1) * 2048);            \
    } while (0)
#define LOADB(d, kk) do {                                                         \
    _Pragma("unroll") for (int ni = 0; ni < 4; ni++)                              \
        bfr[ni] = *(const bf16x8*)(B_kb[kk] + (d) * 32768 + ni * 2048);           \
    } while (0)

    // vm: 0 = none, 1 = vmcnt(4), 2 = vmcnt(0). sT/sqq: 4 stage slots (sT=NT skips).
#define PHASE(d, kk, h, sT, qA, qB, qC, qD, vm) do {                              \
    if ((h) == 0) LOADB(d, kk);                                                   \
    LOADA(d, kk, h);                                                              \
    STAGE(sT, qA); STAGE(sT, qB); STAGE(sT, qC); STAGE(sT, qD);                   \
    __builtin_amdgcn_s_setprio(1);                                                \
    _Pragma("unroll") for (int j = 0; j < 4; j++)                                 \
    _Pragma("unroll") for (int ni = 0; ni < 4; ni++)                              \
        acc[(h) * 4 + j][ni] = __builtin_amdgcn_mfma_f32_16x16x32_bf16(           \
            afr[j], bfr[ni], acc[(h) * 4 + j][ni], 0, 0, 0);                      \
    __builtin_amdgcn_s_setprio(0);                                                \
    if ((vm) == 1) asm volatile("s_waitcnt vmcnt(4)" ::: "memory");               \
    if ((vm) == 2) asm volatile("s_waitcnt vmcnt(0)" ::: "memory");               \
    __builtin_amdgcn_s_barrier();                                                 \
  } while (0)

    // prologue: tile0 (A q0-3, B q4-7), tile1 B q4-7; vmcnt(4) forces tile0.
    STAGE(0, 0); STAGE(0, 1); STAGE(0, 2); STAGE(0, 3);
    STAGE(0, 4); STAGE(0, 5); STAGE(0, 6); STAGE(0, 7);
    STAGE(1, 4); STAGE(1, 5); STAGE(1, 6); STAGE(1, 7);
    asm volatile("s_waitcnt vmcnt(4)" ::: "memory");
    __builtin_amdgcn_s_barrier();

    // main: iter i computes tiles E=2i (pos0-3, buf0) and E+1 (pos4-7, buf1).
    // Stages: pos0 A[E+1], pos3 B[E+2], pos4 A[E+2], pos7 B[E+3].
#pragma unroll 1
    for (int i = 0; i < NT / 2 - 1; i++) {
        int E = 2 * i;
        PHASE(0, 0, 0, E + 1, 0, 1, 2, 3, 0);   // stage A[E+1]
        PHASE(0, 0, 1, NT, 0, 0, 0, 0, 0);
        PHASE(0, 1, 0, NT, 0, 0, 0, 0, 0);
        PHASE(0, 1, 1, E + 2, 4, 5, 6, 7, 1);   // stage B[E+2]; vmcnt(4)
        PHASE(1, 0, 0, E + 2, 0, 1, 2, 3, 0);   // stage A[E+2]
        PHASE(1, 0, 1, NT, 0, 0, 0, 0, 0);
        PHASE(1, 1, 0, NT, 0, 0, 0, 0, 0);
        PHASE(1, 1, 1, E + 3, 4, 5, 6, 7, 1);   // stage B[E+3]; vmcnt(4)
    }

    // peeled last iter (tiles NT-2, NT-1): pos0 stages A[NT-1]; vmcnt(0) at pos3.
    PHASE(0, 0, 0, NT - 1, 0, 1, 2, 3, 0);
    PHASE(0, 0, 1, NT, 0, 0, 0, 0, 0);
    PHASE(0, 1, 0, NT, 0, 0, 0, 0, 0);
    PHASE(0, 1, 1, NT, 0, 0, 0, 0, 2);          // vmcnt(0): A[NT-1] landed
    PHASE(1, 0, 0, NT, 0, 0, 0, 0, 0);
    PHASE(1, 0, 1, NT, 0, 0, 0, 0, 0);
    PHASE(1, 1, 0, NT, 0, 0, 0, 0, 0);
    PHASE(1, 1, 1, NT, 0, 0, 0, 0, 0);
#undef PHASE
#undef LOADA
#undef LOADB

    // C write: acc[h*4+j][ni] -> row = m0 + h*128 + (j>>1)*64 + wm*32 + (j&1)*16 + fq*4 + r
    int fq = lane >> 4;
#pragma unroll
    for (int h = 0; h < 2; h++) {
#pragma unroll
        for (int j = 0; j < 4; j++) {
#pragma unroll
            for (int ni = 0; ni < 4; ni++) {
#pragma unroll
                for (int r = 0; r < 4; r++) {
                    size_t crow = m0 + h * 128 + (j >> 1) * 64 + wm * 32 + (j & 1) * 16 + fq * 4 + r;
                    C[crow * N_DIM + n0 + wn * 64 + ni * 16 + lr] = acc[h * 4 + j][ni][r];
                }
            }
        }
    }
}

extern "C" void kernel_launch(void* const* d_in, const int* in_sizes, int n_in,
                              void* d_out, int out_size, void* d_ws, size_t ws_size,
                              hipStream_t stream) {
    const float* x = (const float*)d_in[0];
    const float* w = (const float*)d_in[1];
    float* out = (float*)d_out;

    ushort* wq = (ushort*)d_ws;                                        // 32 MiB
    ushort* xq = (ushort*)((char*)d_ws + (size_t)N_DIM * K_DIM * 2);   // 64 MiB

    hipLaunchKernelGGL(w_dequant, dim3((N_DIM * K_DIM / 128) / 4), dim3(256), 0, stream, w, wq);
    hipLaunchKernelGGL(act_qdq, dim3(M_DIM), dim3(256), 0, stream, x, xq);
    hipLaunchKernelGGL(gemm_bt8, dim3((M_DIM / BM) * (N_DIM / BN)), dim3(512), 0, stream, xq, wq, out);
}

// Round 23
// 293.422 us; speedup vs baseline: 1.0526x; 1.0526x over previous
//
#include <hip/hip_runtime.h>
#include <hip/hip_bf16.h>
#include <cfloat>

typedef __attribute__((ext_vector_type(8))) short bf16x8;
typedef __attribute__((ext_vector_type(4))) float f32x4;

#define M_DIM 8192
#define N_DIM 4096
#define K_DIM 4096

__device__ inline ushort f2bf(float f) {
    unsigned u = __float_as_uint(f);
    unsigned r = (u + 0x7FFFu + ((u >> 16) & 1u)) >> 16;
    return (ushort)r;
}

// swizzle: XOR 16B-slot index (bits 4-6) with row low bits (bits 7-9). Involution.
#define SWZ(x) ((x) ^ ((((x) >> 7) & 7) << 4))

// ---------------- fused quant kernel ----------------
// blocks 0..2047: activation rows (one WAVE per row, float4 x16/lane, wave-only reduce)
// blocks 2048..3071: weight groups (128 groups/block; half-wave per group, float4 loads)
__global__ __launch_bounds__(256) void quant_fused(const float* __restrict__ x,
                                                   ushort* __restrict__ xq,
                                                   const float* __restrict__ wgt,
                                                   ushort* __restrict__ wq) {
    int b = blockIdx.x;
    int t = threadIdx.x;
    int w = t >> 6, lane = t & 63;
    if (b < 2048) {
        // ---- activation: row = b*4 + w ----
        int row = b * 4 + w;
        const float4* xr = (const float4*)(x + (size_t)row * K_DIM);
        ushort4* xo = (ushort4*)(xq + (size_t)row * K_DIM);
        float4 v[16];
        float mn = FLT_MAX, mx = -FLT_MAX;
#pragma unroll
        for (int i = 0; i < 16; i++) {
            v[i] = xr[lane + i * 64];
            mn = fminf(mn, fminf(fminf(v[i].x, v[i].y), fminf(v[i].z, v[i].w)));
            mx = fmaxf(mx, fmaxf(fmaxf(v[i].x, v[i].y), fmaxf(v[i].z, v[i].w)));
        }
#pragma unroll
        for (int s = 1; s < 64; s <<= 1) {
            mn = fminf(mn, __shfl_xor(mn, s));
            mx = fmaxf(mx, __shfl_xor(mx, s));
        }
        float scale = (mx - mn) / 255.0f;
        float zero  = -128.0f - rintf(mn / scale);
#pragma unroll
        for (int i = 0; i < 16; i++) {
            ushort4 o;
            float q;
            q = fminf(fmaxf(rintf(v[i].x / scale) + zero, -128.0f), 127.0f); o.x = f2bf((q - zero) * scale);
            q = fminf(fmaxf(rintf(v[i].y / scale) + zero, -128.0f), 127.0f); o.y = f2bf((q - zero) * scale);
            q = fminf(fmaxf(rintf(v[i].z / scale) + zero, -128.0f), 127.0f); o.z = f2bf((q - zero) * scale);
            q = fminf(fmaxf(rintf(v[i].w / scale) + zero, -128.0f), 127.0f); o.w = f2bf((q - zero) * scale);
            xo[lane + i * 64] = o;
        }
    } else {
        // ---- weights: 128 groups per block; group = 128 floats = 32 lanes x float4 ----
        int wb = b - 2048;
        int half = lane >> 5, l31 = lane & 31;
#pragma unroll 2
        for (int it = 0; it < 16; it++) {
            int g = wb * 128 + w * 32 + it * 2 + half;
            float4 v = ((const float4*)wgt)[(size_t)g * 32 + l31];
            float mn = fminf(fminf(v.x, v.y), fminf(v.z, v.w));
            float mx = fmaxf(fmaxf(v.x, v.y), fmaxf(v.z, v.w));
#pragma unroll
            for (int s = 1; s < 32; s <<= 1) {   // stays within the 32-lane half
                mn = fminf(mn, __shfl_xor(mn, s));
                mx = fmaxf(mx, __shfl_xor(mx, s));
            }
            float scale = (mx - mn) / 15.0f;
            float zero  = -8.0f - rintf(mn / scale);
            ushort4 o;
            float q;
            q = fminf(fmaxf(rintf(v.x / scale) + zero, -8.0f), 7.0f); o.x = f2bf((q - zero) * scale);
            q = fminf(fmaxf(rintf(v.y / scale) + zero, -8.0f), 7.0f); o.y = f2bf((q - zero) * scale);
            q = fminf(fmaxf(rintf(v.z / scale) + zero, -8.0f), 7.0f); o.z = f2bf((q - zero) * scale);
            q = fminf(fmaxf(rintf(v.w / scale) + zero, -8.0f), 7.0f); o.w = f2bf((q - zero) * scale);
            ((ushort4*)wq)[(size_t)g * 32 + l31] = o;
        }
    }
}

// ---------------- kernel 3: 256x256 8-phase bf16 GEMM (r19 verbatim — session best) ---
// Single end-barrier per phase; counted vmcnt(6) at ph3/ph7; r5 slot table; hoisted
// swizzled addresses; kk=0-first reads; compiler-counted lgkm before MFMAs.
#define BM 256
#define BN 256
#define BK 64
#define NT (K_DIM / BK)   /* 64 K-tiles */

__global__ __launch_bounds__(512, 1) void gemm_bt8(const ushort* __restrict__ A,
                                                   const ushort* __restrict__ B,
                                                   float* __restrict__ C) {
    __shared__ __align__(16) ushort As[2][BM * BK];   // quarter rq at byte rq*8192
    __shared__ __align__(16) ushort Bs[2][BN * BK];

    const int nbx = N_DIM / BN;                 // 16
    const int nwg = (M_DIM / BM) * nbx;         // 512 (%8==0)
    int bid = blockIdx.x;
    bid = (bid & 7) * (nwg / 8) + (bid >> 3);   // bijective XCD swizzle
    int mb = bid / nbx, nb = bid % nbx;
    size_t m0 = (size_t)mb * BM, n0 = (size_t)nb * BN;

    const int t = threadIdx.x;
    const int w = t >> 6, lane = t & 63;
    const int wm = w >> 2, wn = w & 3;          // 2 x 4 wave grid
    const int lr = lane & 15;
    const int lk = (lane >> 4) << 3;

    const ushort* Ab = A + m0 * K_DIM;
    const ushort* Bb = B + n0 * K_DIM;

    // hoisted swizzled lane-parts: phys = row*128 + (colbyte ^ ((lr&7)<<4)), row%8==lr%8
    const int mask7 = (lr & 7) << 4;
    const int lp0 = lr * 128 + ((lk * 2) ^ mask7);          // kk=0
    const int lp1 = lr * 128 + ((64 + lk * 2) ^ mask7);     // kk=1
    const char* A_k0 = (const char*)As + wm * 4096 + lp0;   // + wm*32 rows baked in
    const char* A_k1 = (const char*)As + wm * 4096 + lp1;
    const char* B_k0 = (const char*)Bs + wn * 8192 + lp0;   // + wn*64 rows baked in
    const char* B_k1 = (const char*)Bs + wn * 8192 + lp1;

    // hoisted stage source offsets (elements) and dest bytes per row-quarter
    int off_q[4], dst_q[4];
#pragma unroll
    for (int rq = 0; rq < 4; rq++) {
        int base = rq * 8192 + w * 1024;
        int lg = SWZ(base + lane * 16);
        off_q[rq] = (lg >> 7) * K_DIM + ((lg & 127) >> 1);
        dst_q[rq] = base;
    }

    // stage one 8KB quarter: qq 0-3 = A rows qq*64.., qq 4-7 = B rows (qq-4)*64..
    auto STAGE = [&](int T, int qq) {
        if (T >= NT) return;
        int d = T & 1;
        bool isA = qq < 4;
        int rq = qq & 3;
        ushort* l = isA ? As[d] : Bs[d];
        const ushort* g = (isA ? Ab : Bb) + (size_t)T * BK + off_q[rq];
        __builtin_amdgcn_global_load_lds(
            (const __attribute__((address_space(1))) unsigned int*)g,
            (__attribute__((address_space(3))) unsigned int*)((char*)l + dst_q[rq]),
            16, 0, 0);
    };

    f32x4 acc[8][4] = {};
    bf16x8 afr[2][2];   // [ii][kk] read each phase
    bf16x8 bfr[4][2];   // [ni][kk] read at q0, live 4 phases

    // kk=0-first read ordering (operands of the first MFMAs land first)
#define LOADA0(d, q) do {                                                         \
    _Pragma("unroll") for (int ii = 0; ii < 2; ii++)                              \
        afr[ii][0] = *(const bf16x8*)(A_k0 + (d) * 32768 + ((q) * 64 + ii * 16) * 128); \
    } while (0)
#define LOADA1(d, q) do {                                                         \
    _Pragma("unroll") for (int ii = 0; ii < 2; ii++)                              \
        afr[ii][1] = *(const bf16x8*)(A_k1 + (d) * 32768 + ((q) * 64 + ii * 16) * 128); \
    } while (0)
#define LOADB0(d) do {                                                            \
    _Pragma("unroll") for (int ni = 0; ni < 4; ni++)                              \
        bfr[ni][0] = *(const bf16x8*)(B_k0 + (d) * 32768 + ni * 2048);            \
    } while (0)
#define LOADB1(d) do {                                                            \
    _Pragma("unroll") for (int ni = 0; ni < 4; ni++)                              \
        bfr[ni][1] = *(const bf16x8*)(B_k1 + (d) * 32768 + ni * 2048);            \
    } while (0)

    // vm: 0 = no wait, 1 = vmcnt(6), 2 = vmcnt(0). ONE barrier per phase (at end).
#define PHASE(d, q, sT1, sq1, sT2, sq2, vm) do {                                  \
    LOADA0(d, q);                                                                 \
    if ((q) == 0) LOADB0(d);                                                      \
    LOADA1(d, q);                                                                 \
    if ((q) == 0) LOADB1(d);                                                      \
    STAGE(sT1, sq1);                                                              \
    STAGE(sT2, sq2);                                                              \
    __builtin_amdgcn_s_setprio(1);                                                \
    _Pragma("unroll") for (int kk = 0; kk < 2; kk++)                              \
    _Pragma("unroll") for (int ii = 0; ii < 2; ii++)                              \
    _Pragma("unroll") for (int ni = 0; ni < 4; ni++)                              \
        acc[(q) * 2 + ii][ni] = __builtin_amdgcn_mfma_f32_16x16x32_bf16(          \
            afr[ii][kk], bfr[ni][kk], acc[(q) * 2 + ii][ni], 0, 0, 0);            \
    __builtin_amdgcn_s_setprio(0);                                                \
    if ((vm) == 1) asm volatile("s_waitcnt vmcnt(6)" ::: "memory");               \
    if ((vm) == 2) asm volatile("s_waitcnt vmcnt(0)" ::: "memory");               \
    __builtin_amdgcn_s_barrier();                                                 \
  } while (0)

    // prologue: tile0 all 8 quarters, tile1 B quarters, tile1 A0,A1; tile0 landed
    STAGE(0, 0); STAGE(0, 1); STAGE(0, 2); STAGE(0, 3);
    STAGE(0, 4); STAGE(0, 5); STAGE(0, 6); STAGE(0, 7);
    STAGE(1, 4); STAGE(1, 5); STAGE(1, 6); STAGE(1, 7);
    STAGE(1, 0); STAGE(1, 1);
    asm volatile("s_waitcnt vmcnt(6)" ::: "memory");
    __builtin_amdgcn_s_barrier();

    // main: iters 0..NT/2-2 (r5/r13 slot table; vmcnt(6) only at ph3/ph7)
#pragma unroll 1
    for (int i = 0; i < NT / 2 - 1; i++) {
        int T0 = 2 * i;
        PHASE(0, 0, T0 + 1, 2, T0 + 1, 3, 0);
        PHASE(0, 1, T0 + 2, 4, T0 + 2, 5, 0);
        PHASE(0, 2, T0 + 2, 6, T0 + 2, 7, 0);
        PHASE(0, 3, T0 + 2, 0, T0 + 2, 1, 1);   // vmcnt(6): tile 2i+1 landed
        PHASE(1, 0, T0 + 2, 2, T0 + 2, 3, 0);
        PHASE(1, 1, T0 + 3, 4, T0 + 3, 5, 0);
        PHASE(1, 2, T0 + 3, 6, T0 + 3, 7, 0);
        PHASE(1, 3, T0 + 3, 0, T0 + 3, 1, 1);   // vmcnt(6): tile 2i+2 landed
    }

    // peeled last iter (tiles NT-2, NT-1): stage NT-1's A[2],A[3]; drain at ph3
    PHASE(0, 0, NT - 1, 2, NT - 1, 3, 0);
    PHASE(0, 1, NT, 0, NT, 0, 0);
    PHASE(0, 2, NT, 0, NT, 0, 0);
    PHASE(0, 3, NT, 0, NT, 0, 2);   // vmcnt(0): tile NT-1 landed
    PHASE(1, 0, NT, 0, NT, 0, 0);
    PHASE(1, 1, NT, 0, NT, 0, 0);
    PHASE(1, 2, NT, 0, NT, 0, 0);
    PHASE(1, 3, NT, 0, NT, 0, 0);
#undef PHASE
#undef LOADA0
#undef LOADA1
#undef LOADB0
#undef LOADB1

    // C write: acc[mi][ni], mi = q*2+ii -> row = m0 + (mi>>1)*64 + wm*32 + (mi&1)*16 + fq*4 + r
    int fq = lane >> 4;
#pragma unroll
    for (int mi = 0; mi < 8; mi++) {
#pragma unroll
        for (int ni = 0; ni < 4; ni++) {
#pragma unroll
            for (int r = 0; r < 4; r++) {
                size_t crow = m0 + (mi >> 1) * 64 + wm * 32 + (mi & 1) * 16 + fq * 4 + r;
                C[crow * N_DIM + n0 + wn * 64 + ni * 16 + lr] = acc[mi][ni][r];
            }
        }
    }
}

extern "C" void kernel_launch(void* const* d_in, const int* in_sizes, int n_in,
                              void* d_out, int out_size, void* d_ws, size_t ws_size,
                              hipStream_t stream) {
    const float* x = (const float*)d_in[0];
    const float* w = (const float*)d_in[1];
    float* out = (float*)d_out;

    ushort* wq = (ushort*)d_ws;                                        // 32 MiB
    ushort* xq = (ushort*)((char*)d_ws + (size_t)N_DIM * K_DIM * 2);   // 64 MiB

    hipLaunchKernelGGL(quant_fused, dim3(2048 + 1024), dim3(256), 0, stream, x, xq, w, wq);
    hipLaunchKernelGGL(gemm_bt8, dim3((M_DIM / BM) * (N_DIM / BN)), dim3(512), 0, stream, xq, wq, out);
}